// Round 1
// baseline (177.377 us; speedup 1.0000x reference)
//
#include <hip/hip_runtime.h>

#define P 13
#define NSTATES 8192   // 2^13
#define NPAIRS  4096
#define BLK     512

struct c32 { float re, im; };
__device__ __forceinline__ c32 cmul(c32 a, c32 b){ return {a.re*b.re - a.im*b.im, a.re*b.im + a.im*b.re}; }
__device__ __forceinline__ c32 cadd(c32 a, c32 b){ return {a.re+b.re, a.im+b.im}; }

// Apply a 2x2 complex gate on bit position bp (stride 1<<bp) to the LDS state.
__device__ __forceinline__ void apply1q(float2* st, int bp, c32 u00, c32 u01, c32 u10, c32 u11, int tid)
{
    const int stq = 1 << bp;
    for (int k = tid; k < NPAIRS; k += BLK) {
        int i0 = ((k >> bp) << (bp + 1)) | (k & (stq - 1));
        int i1 = i0 | stq;
        float2 v0 = st[i0], v1 = st[i1];
        c32 a0 = {v0.x, v0.y}, a1 = {v1.x, v1.y};
        c32 r0 = cadd(cmul(u00, a0), cmul(u01, a1));
        c32 r1 = cadd(cmul(u10, a0), cmul(u11, a1));
        st[i0] = make_float2(r0.re, r0.im);
        st[i1] = make_float2(r1.re, r1.im);
    }
}

__global__ __launch_bounds__(BLK) void qlc_kernel(
    const float* __restrict__ h, const float* __restrict__ enc_w,
    const float* __restrict__ enc_b, const float* __restrict__ qw,
    const float* __restrict__ dec_w, const float* __restrict__ alpha,
    float* __restrict__ out, int nlayers)
{
    const int n   = blockIdx.x;   // sample index in [0, B*T)
    const int tid = threadIdx.x;

    __shared__ float2 st[NSTATES];   // 64 KB: the full statevector

    // ---- init |00...0> ----
    for (int i = tid; i < NSTATES; i += BLK) st[i] = make_float2(0.f, 0.f);
    if (tid == 0) st[0] = make_float2(1.f, 0.f);
    __syncthreads();

    const float* hrow_base = h + (size_t)n * (P * 64);

    // ---- encoding: fused RZ(a2)*RY(a1)*RX(a0) per wire (per-sample angles) ----
    for (int p = 0; p < P; ++p) {
        // Redundant per-thread angle computation; addresses are block-uniform
        // -> scalar loads, L1-cached. Avoids needing LDS beyond the state.
        const float* hr = hrow_base + p * 64;
        float a0 = enc_b[0], a1 = enc_b[1], a2 = enc_b[2];
        for (int d = 0; d < 64; ++d) {
            float hv = hr[d];
            a0 = fmaf(hv, enc_w[d],       a0);
            a1 = fmaf(hv, enc_w[64 + d],  a1);
            a2 = fmaf(hv, enc_w[128 + d], a2);
        }
        float x = 0.5f * a0, y = 0.5f * a1, z = 0.5f * a2;
        float cx = cosf(x), sx = sinf(x);
        float cy = cosf(y), sy = sinf(y);
        float cz = cosf(z), sz = sinf(z);
        // A = RY(y) * RX(x)
        c32 A00 = { cy * cx,  sy * sx};
        c32 A01 = {-sy * cx, -cy * sx};
        c32 A10 = { sy * cx, -cy * sx};
        c32 A11 = { cy * cx, -sy * sx};
        // U = RZ(z) * A  (row0 *= e^{-iz}, row1 *= e^{+iz})
        c32 em = {cz, -sz}, ep = {cz, sz};
        c32 u00 = cmul(em, A00), u01 = cmul(em, A01);
        c32 u10 = cmul(ep, A10), u11 = cmul(ep, A11);
        apply1q(st, 12 - p, u00, u01, u10, u11, tid);
        __syncthreads();
    }

    // ---- variational layers: fused RY(w2)*RZ(w1)*RY(w0), then ring CNOTs ----
    for (int l = 0; l < nlayers; ++l) {
        for (int p = 0; p < P; ++p) {
            const float* w = qw + (size_t)(l * P + p) * 3;
            float a = 0.5f * w[0], b = 0.5f * w[1], c = 0.5f * w[2];
            float ca = cosf(a), sa = sinf(a);
            float cb = cosf(b), sb = sinf(b);
            float cc = cosf(c), sc = sinf(c);
            // B = RZ(b) * RY(a)
            c32 B00 = { ca * cb, -ca * sb};
            c32 B01 = {-sa * cb,  sa * sb};
            c32 B10 = { sa * cb,  sa * sb};
            c32 B11 = { ca * cb,  ca * sb};
            // V = RY(c) * B   (RY is real)
            c32 u00 = {cc * B00.re - sc * B10.re, cc * B00.im - sc * B10.im};
            c32 u01 = {cc * B01.re - sc * B11.re, cc * B01.im - sc * B11.im};
            c32 u10 = {sc * B00.re + cc * B10.re, sc * B00.im + cc * B10.im};
            c32 u11 = {sc * B01.re + cc * B11.re, sc * B01.im + cc * B11.im};
            apply1q(st, 12 - p, u00, u01, u10, u11, tid);
            __syncthreads();
        }
        for (int i = 0; i < P; ++i) {
            int c = i, t = (i + 1) % P;
            int bc = 12 - c, bt = 12 - t;
            int lo = bc < bt ? bc : bt;
            int hi = bc < bt ? bt : bc;
            // enumerate the 2048 indices with bit_bc=1, bit_bt=0; swap with bt=1
            for (int k = tid; k < NSTATES / 4; k += BLK) {
                int idx = ((k >> lo) << (lo + 1)) | (k & ((1 << lo) - 1));
                idx = ((idx >> hi) << (hi + 1)) | (idx & ((1 << hi) - 1));
                idx |= (1 << bc);
                int jdx = idx | (1 << bt);
                float2 va = st[idx], vb = st[jdx];
                st[idx] = vb;
                st[jdx] = va;
            }
            __syncthreads();
        }
    }

    // ---- expectation values <Z_w> = sum probs * (1 - 2*bit_w) ----
    float ev[P];
#pragma unroll
    for (int w = 0; w < P; ++w) ev[w] = 0.f;
    for (int i = tid; i < NSTATES; i += BLK) {
        float2 v = st[i];
        float pr = v.x * v.x + v.y * v.y;
#pragma unroll
        for (int w = 0; w < P; ++w)
            ev[w] += ((i >> (12 - w)) & 1) ? -pr : pr;
    }
    __syncthreads();   // all state reads done; safe to reuse LDS as scratch

#pragma unroll
    for (int w = 0; w < P; ++w)
        for (int off = 32; off > 0; off >>= 1)
            ev[w] += __shfl_down(ev[w], off, 64);

    float* scratch = (float*)st;
    int wave = tid >> 6, lane = tid & 63;
    if (lane == 0) {
#pragma unroll
        for (int w = 0; w < P; ++w) scratch[wave * P + w] = ev[w];
    }
    __syncthreads();
    if (tid < P) {
        float s = 0.f;
        for (int wv = 0; wv < BLK / 64; ++wv) s += scratch[wv * P + tid];
        scratch[128 + tid] = s;   // final expvals parked at offset 128
    }
    __syncthreads();

    // ---- decode + residual: out = h + alpha * ev[p] * dec_w[d] ----
    float al = alpha[0];
    for (int idx = tid; idx < P * 64; idx += BLK) {
        int pp = idx >> 6, d = idx & 63;
        size_t off = (size_t)n * (P * 64) + idx;
        out[off] = h[off] + al * scratch[128 + pp] * dec_w[d];
    }
}

extern "C" void kernel_launch(void* const* d_in, const int* in_sizes, int n_in,
                              void* d_out, int out_size, void* d_ws, size_t ws_size,
                              hipStream_t stream) {
    const float* h     = (const float*)d_in[0];
    const float* enc_w = (const float*)d_in[1];
    const float* enc_b = (const float*)d_in[2];
    const float* qw    = (const float*)d_in[3];
    const float* dec_w = (const float*)d_in[4];
    const float* alpha = (const float*)d_in[5];
    float* out = (float*)d_out;

    int N = in_sizes[0] / (P * 64);        // B*T samples
    int L = in_sizes[3] / (P * 3);         // variational layers

    qlc_kernel<<<N, BLK, 0, stream>>>(h, enc_w, enc_b, qw, dec_w, alpha, out, L);
}

// Round 2
// 91.110 us; speedup vs baseline: 1.9468x; 1.9468x over previous
//
#include <hip/hip_runtime.h>

#define P   13
#define BLK 512
#define NH  (P * 64)   // 832 floats per sample row

typedef float2 c2;

__device__ __forceinline__ c2 cmul2(c2 a, c2 b) {
    return make_float2(a.x * b.x - a.y * b.y, a.x * b.y + a.y * b.x);
}
__device__ __forceinline__ c2 cfma2(c2 a, c2 b, c2 c) {  // a*b + c
    return make_float2(fmaf(a.x, b.x, fmaf(-a.y, b.y, c.x)),
                       fmaf(a.x, b.y, fmaf( a.y, b.x, c.y)));
}
__device__ __forceinline__ c2 shflx2(c2 v, int m) {
    c2 r;
    r.x = __shfl_xor(v.x, m, 64);
    r.y = __shfl_xor(v.y, m, 64);
    return r;
}

// State layout: amplitude index i = (tid<<4) | r,  i has 13 bits.
//   bits 0..3  = r bits      -> wires 12,11,10,9   (register-local)
//   bits 4..9  = lane bits   -> wires 8..3         (shuffle)
//   bits 10..12= wave bits   -> wires 2,1,0        (LDS staging)
// (wire w lives at bit 12-w; wire 0 = MSB, matching the reference.)

__global__ __launch_bounds__(BLK) void qlc_kernel(
    const float* __restrict__ h, const float* __restrict__ enc_w,
    const float* __restrict__ enc_b, const float* __restrict__ qw,
    const float* __restrict__ dec_w, const float* __restrict__ alpha,
    float* __restrict__ out, int nlayers)
{
    const int n    = blockIdx.x;
    const int tid  = threadIdx.x;
    const int lane = tid & 63;
    const int wv   = tid >> 6;

    __shared__ float lds[16384];          // 64 KB, multi-purpose
    float* re = lds;                      // staging plane (8192 floats)
    float* im = lds + 8192;               // staging plane (8192 floats)

    c2 s[16];

    // ================= Phase 1: per-wire 2-vectors, product state ==========
    // Encoding U = RZ*RY*RX applied to |0> gives col0 of U; layer-0 gates
    // V = RY*RZ*RY fold in before any CNOT. State = tensor product.
    for (int p = wv; p < P; p += 8) {
        float hv = h[(size_t)n * NH + p * 64 + lane];
        float a0 = hv * enc_w[lane];
        float a1 = hv * enc_w[64 + lane];
        float a2 = hv * enc_w[128 + lane];
#pragma unroll
        for (int m = 32; m; m >>= 1) {
            a0 += __shfl_xor(a0, m, 64);
            a1 += __shfl_xor(a1, m, 64);
            a2 += __shfl_xor(a2, m, 64);
        }
        float x = 0.5f * (a0 + enc_b[0]);
        float y = 0.5f * (a1 + enc_b[1]);
        float z = 0.5f * (a2 + enc_b[2]);
        float cx = cosf(x), sx = sinf(x);
        float cy = cosf(y), sy = sinf(y);
        float cz = cosf(z), sz = sinf(z);
        c2 em = {cz, -sz}, ep = {cz, sz};
        c2 u0 = cmul2(em, make_float2(cy * cx,  sy * sx));   // U00
        c2 u1 = cmul2(ep, make_float2(sy * cx, -cy * sx));   // U10
        c2 w0 = u0, w1 = u1;
        if (nlayers > 0) {
            const float* w = qw + p * 3;   // layer 0
            float a = 0.5f * w[0], b = 0.5f * w[1], c = 0.5f * w[2];
            float ca = cosf(a), sa = sinf(a);
            float cb = cosf(b), sb = sinf(b);
            float cc = cosf(c), sc = sinf(c);
            c2 B00 = { ca * cb, -ca * sb};
            c2 B01 = {-sa * cb,  sa * sb};
            c2 B10 = { sa * cb,  sa * sb};
            c2 B11 = { ca * cb,  ca * sb};
            c2 V00 = {cc * B00.x - sc * B10.x, cc * B00.y - sc * B10.y};
            c2 V01 = {cc * B01.x - sc * B11.x, cc * B01.y - sc * B11.y};
            c2 V10 = {sc * B00.x + cc * B10.x, sc * B00.y + cc * B10.y};
            c2 V11 = {sc * B01.x + cc * B11.x, sc * B01.y + cc * B11.y};
            w0 = cfma2(V00, u0, cmul2(V01, u1));
            w1 = cfma2(V10, u0, cmul2(V11, u1));
        }
        if (lane == 0) {
            lds[p * 4 + 0] = w0.x; lds[p * 4 + 1] = w0.y;
            lds[p * 4 + 2] = w1.x; lds[p * 4 + 3] = w1.y;
        }
    }
    __syncthreads();
    {
        c2 pref = {1.f, 0.f};
#pragma unroll
        for (int w = 0; w < 9; ++w) {           // wires 0..8: thread bits
            int b = (tid >> (8 - w)) & 1;
            c2 vp = {lds[w * 4 + b * 2], lds[w * 4 + b * 2 + 1]};
            pref = cmul2(pref, vp);
        }
        c2 w9[2], w10[2], w11[2], w12[2];
#pragma unroll
        for (int b = 0; b < 2; ++b) {
            w9[b]  = {lds[ 9 * 4 + b * 2], lds[ 9 * 4 + b * 2 + 1]};
            w10[b] = {lds[10 * 4 + b * 2], lds[10 * 4 + b * 2 + 1]};
            w11[b] = {lds[11 * 4 + b * 2], lds[11 * 4 + b * 2 + 1]};
            w12[b] = {lds[12 * 4 + b * 2], lds[12 * 4 + b * 2 + 1]};
        }
#pragma unroll
        for (int r = 0; r < 16; ++r)
            s[r] = cmul2(pref, cmul2(cmul2(w9[(r >> 3) & 1], w10[(r >> 2) & 1]),
                                     cmul2(w11[(r >> 1) & 1], w12[r & 1])));
    }

    // ================= Ring CNOT chain =====================================
    auto cnot_chain = [&]() {
        // (0,1): control tid bit8, target tid bit7 -> LDS swap (half state)
        __syncthreads();
        {
            int c = (tid >> 8) & 1;
            if (c) {
#pragma unroll
                for (int r = 0; r < 16; ++r) { re[r * 512 + tid] = s[r].x; im[r * 512 + tid] = s[r].y; }
            }
            __syncthreads();
            if (c) {
                int p = tid ^ 128;
#pragma unroll
                for (int r = 0; r < 16; ++r) s[r] = make_float2(re[r * 512 + p], im[r * 512 + p]);
            }
        }
        // (1,2): control tid bit7, target tid bit6 -> LDS swap
        __syncthreads();
        {
            int c = (tid >> 7) & 1;
            if (c) {
#pragma unroll
                for (int r = 0; r < 16; ++r) { re[r * 512 + tid] = s[r].x; im[r * 512 + tid] = s[r].y; }
            }
            __syncthreads();
            if (c) {
                int p = tid ^ 64;
#pragma unroll
                for (int r = 0; r < 16; ++r) s[r] = make_float2(re[r * 512 + p], im[r * 512 + p]);
            }
        }
        // (2,3): control tid bit6 (wave-uniform), target lane bit5
        {
            int c = (tid >> 6) & 1;
#pragma unroll
            for (int r = 0; r < 16; ++r) { c2 pv = shflx2(s[r], 32); if (c) s[r] = pv; }
        }
        // (3,4)..(7,8): control lane bit (5..1), target lane bit (4..0)
#pragma unroll
        for (int k = 0; k < 5; ++k) {
            int cb = 5 - k, m = 1 << (4 - k);
            int c = (lane >> cb) & 1;
#pragma unroll
            for (int r = 0; r < 16; ++r) { c2 pv = shflx2(s[r], m); if (c) s[r] = pv; }
        }
        // (8,9): control lane bit0, target r bit3
        {
            int c = lane & 1;
#pragma unroll
            for (int r = 0; r < 8; ++r) {
                c2 a = s[r], b = s[r + 8];
                s[r]     = c ? b : a;
                s[r + 8] = c ? a : b;
            }
        }
        // (9,10),(10,11),(11,12): compile-time register permutations
#pragma unroll
        for (int r = 0; r < 16; ++r)
            if ((r & 8) && !(r & 4)) { c2 t = s[r]; s[r] = s[r | 4]; s[r | 4] = t; }
#pragma unroll
        for (int r = 0; r < 16; ++r)
            if ((r & 4) && !(r & 2)) { c2 t = s[r]; s[r] = s[r | 2]; s[r | 2] = t; }
#pragma unroll
        for (int r = 0; r < 16; ++r)
            if ((r & 2) && !(r & 1)) { c2 t = s[r]; s[r] = s[r | 1]; s[r | 1] = t; }
        // (12,0): control r bit0 (odd regs), target tid bit8 -> LDS swap
        __syncthreads();
#pragma unroll
        for (int r = 1; r < 16; r += 2) { re[r * 512 + tid] = s[r].x; im[r * 512 + tid] = s[r].y; }
        __syncthreads();
        {
            int p = tid ^ 256;
#pragma unroll
            for (int r = 1; r < 16; r += 2) s[r] = make_float2(re[r * 512 + p], im[r * 512 + p]);
        }
    };

    // ================= Full single-qubit gate pass (layers >= 1) ===========
    auto apply_layer = [&](int l) {
        __syncthreads();                       // prior staging reads done
        if (tid < P) {                         // one thread per wire matrix
            const float* w = qw + (size_t)(l * P + tid) * 3;
            float a = 0.5f * w[0], b = 0.5f * w[1], c = 0.5f * w[2];
            float ca = cosf(a), sa = sinf(a);
            float cb = cosf(b), sb = sinf(b);
            float cc = cosf(c), sc = sinf(c);
            c2 B00 = { ca * cb, -ca * sb};
            c2 B01 = {-sa * cb,  sa * sb};
            c2 B10 = { sa * cb,  sa * sb};
            c2 B11 = { ca * cb,  ca * sb};
            float* m = lds + tid * 8;
            m[0] = cc * B00.x - sc * B10.x; m[1] = cc * B00.y - sc * B10.y;  // u00
            m[2] = cc * B01.x - sc * B11.x; m[3] = cc * B01.y - sc * B11.y;  // u01
            m[4] = sc * B00.x + cc * B10.x; m[5] = sc * B00.y + cc * B10.y;  // u10
            m[6] = sc * B01.x + cc * B11.x; m[7] = sc * B01.y + cc * B11.y;  // u11
        }
        __syncthreads();
        // wires 9..12: register butterflies (r bit 12-p)
#pragma unroll
        for (int p = 9; p <= 12; ++p) {
            int b = 12 - p;
            c2 u00 = {lds[p * 8 + 0], lds[p * 8 + 1]}, u01 = {lds[p * 8 + 2], lds[p * 8 + 3]};
            c2 u10 = {lds[p * 8 + 4], lds[p * 8 + 5]}, u11 = {lds[p * 8 + 6], lds[p * 8 + 7]};
#pragma unroll
            for (int r = 0; r < 16; ++r)
                if (!(r & (1 << b))) {
                    int r1 = r | (1 << b);
                    c2 a0 = s[r], a1 = s[r1];
                    s[r]  = cfma2(u00, a0, cmul2(u01, a1));
                    s[r1] = cfma2(u10, a0, cmul2(u11, a1));
                }
        }
        // wires 3..8: shuffle gates (lane bit 8-p)
#pragma unroll
        for (int p = 3; p <= 8; ++p) {
            int lb = 8 - p;
            c2 u00 = {lds[p * 8 + 0], lds[p * 8 + 1]}, u01 = {lds[p * 8 + 2], lds[p * 8 + 3]};
            c2 u10 = {lds[p * 8 + 4], lds[p * 8 + 5]}, u11 = {lds[p * 8 + 6], lds[p * 8 + 7]};
            int mb = (lane >> lb) & 1;
            c2 ua = mb ? u11 : u00;
            c2 ub = mb ? u10 : u01;
#pragma unroll
            for (int r = 0; r < 16; ++r) {
                c2 pv = shflx2(s[r], 1 << lb);
                s[r] = cfma2(ua, s[r], cmul2(ub, pv));
            }
        }
        // wires 0..2: LDS staging gates (tid bit 8-p); preload mats first
        c2 um[3][4];
#pragma unroll
        for (int p = 0; p < 3; ++p) {
            um[p][0] = {lds[p * 8 + 0], lds[p * 8 + 1]};
            um[p][1] = {lds[p * 8 + 2], lds[p * 8 + 3]};
            um[p][2] = {lds[p * 8 + 4], lds[p * 8 + 5]};
            um[p][3] = {lds[p * 8 + 6], lds[p * 8 + 7]};
        }
#pragma unroll
        for (int p = 0; p < 3; ++p) {
            int shift = 8 - p;                 // tid bit
            __syncthreads();                   // mats consumed / prior reads done
#pragma unroll
            for (int r = 0; r < 16; ++r) { re[r * 512 + tid] = s[r].x; im[r * 512 + tid] = s[r].y; }
            __syncthreads();
            int pt = tid ^ (1 << shift);
            int mb = (tid >> shift) & 1;
            c2 ua = mb ? um[p][3] : um[p][0];
            c2 ub = mb ? um[p][2] : um[p][1];
#pragma unroll
            for (int r = 0; r < 16; ++r) {
                c2 pv = make_float2(re[r * 512 + pt], im[r * 512 + pt]);
                s[r] = cfma2(ua, s[r], cmul2(ub, pv));
            }
        }
    };

    if (nlayers > 0) cnot_chain();
    for (int l = 1; l < nlayers; ++l) { apply_layer(l); cnot_chain(); }

    // ================= Measure <Z_w> + decode ==============================
    float tot = 0.f, e9 = 0.f, e10 = 0.f, e11 = 0.f, e12 = 0.f;
#pragma unroll
    for (int r = 0; r < 16; ++r) {
        float pr = fmaf(s[r].x, s[r].x, s[r].y * s[r].y);
        tot += pr;
        e9  += (r & 8) ? -pr : pr;
        e10 += (r & 4) ? -pr : pr;
        e11 += (r & 2) ? -pr : pr;
        e12 += (r & 1) ? -pr : pr;
    }
    float v[13];
#pragma unroll
    for (int w = 0; w < 9; ++w) v[w] = ((tid >> (8 - w)) & 1) ? -tot : tot;
    v[9] = e9; v[10] = e10; v[11] = e11; v[12] = e12;
#pragma unroll
    for (int w = 0; w < 13; ++w) {
#pragma unroll
        for (int m = 32; m; m >>= 1) v[w] += __shfl_xor(v[w], m, 64);
    }
    __syncthreads();                           // staging reads done; reuse LDS
    if (lane == 0) {
#pragma unroll
        for (int w = 0; w < 13; ++w) lds[wv * 13 + w] = v[w];
    }
    __syncthreads();
    if (tid < 13) {
        float sum = 0.f;
        for (int q = 0; q < 8; ++q) sum += lds[q * 13 + tid];
        lds[256 + tid] = sum;
    }
    __syncthreads();
    float al = alpha[0];
    for (int idx = tid; idx < NH; idx += BLK) {
        size_t off = (size_t)n * NH + idx;
        out[off] = fmaf(al * lds[256 + (idx >> 6)], dec_w[idx & 63], h[off]);
    }
}

extern "C" void kernel_launch(void* const* d_in, const int* in_sizes, int n_in,
                              void* d_out, int out_size, void* d_ws, size_t ws_size,
                              hipStream_t stream) {
    const float* h     = (const float*)d_in[0];
    const float* enc_w = (const float*)d_in[1];
    const float* enc_b = (const float*)d_in[2];
    const float* qw    = (const float*)d_in[3];
    const float* dec_w = (const float*)d_in[4];
    const float* alpha = (const float*)d_in[5];
    float* out = (float*)d_out;

    int N = in_sizes[0] / NH;          // B*T samples
    int L = in_sizes[3] / (P * 3);     // variational layers

    qlc_kernel<<<N, BLK, 0, stream>>>(h, enc_w, enc_b, qw, dec_w, alpha, out, L);
}

// Round 3
// 81.157 us; speedup vs baseline: 2.1856x; 1.1226x over previous
//
#include <hip/hip_runtime.h>

#define P   13
#define BLK 512
#define NH  (P * 64)

typedef float2 c2;

__device__ __forceinline__ c2 cmul2(c2 a, c2 b) {
    return make_float2(a.x * b.x - a.y * b.y, a.x * b.y + a.y * b.x);
}
__device__ __forceinline__ c2 cfma2(c2 a, c2 b, c2 c) {  // a*b + c
    return make_float2(fmaf(a.x, b.x, fmaf(-a.y, b.y, c.x)),
                       fmaf(a.x, b.y, fmaf( a.y, b.x, c.y)));
}
__device__ __forceinline__ c2 shflx2(c2 v, int m) {
    c2 r; r.x = __shfl_xor(v.x, m, 64); r.y = __shfl_xor(v.y, m, 64); return r;
}

// ---------------- GF(2) frame tracking (compile-time verified) -------------
// Physical address p = (tid<<4)|r, 13 bits. Logical index bit b = parity(rowF[b]&p).
// CNOT(c,t) [bits bc=12-c, bt=12-t]: rowF[bt]^=rowF[bc]; colG[bc]^=colG[bt].
// Gate on logical bit b pairs p <-> p ^ colG[b]; the beta (which side is |0>)
// is parity(rowF[b]&p). F0 below is chosen so that after one ring-CNOT chain
// every gate mask colG1[b] is a SINGLE physical bit (and rowF1[b] the same bit):
//   phi(0)=10, phi(1)=11, phi(k)=k-2 (k=2..11), phi(12)=12.
struct RowSet { unsigned r[13]; };
constexpr RowSet chain_rows(RowSet f) {
    for (int i = 0; i < 13; ++i) { int bc = 12 - i; int bt = (i == 12) ? 12 : (11 - i); f.r[bt] ^= f.r[bc]; }
    return f;
}
constexpr RowSet chain_cols(RowSet g) {
    for (int i = 0; i < 13; ++i) { int bc = 12 - i; int bt = (i == 12) ? 12 : (11 - i); g.r[bc] ^= g.r[bt]; }
    return g;
}
constexpr RowSet R0c {{0x0C00,0x0801,0x0003,0x0006,0x000C,0x0018,0x0030,0x0060,0x00C0,0x0180,0x0300,0x1600,0x1400}};
constexpr RowSet G0c {{0x1400,0x1C00,0x1C01,0x1C03,0x1C07,0x1C0F,0x1C1F,0x1C3F,0x1C7F,0x1CFF,0x1DFF,0x1FFF,0x0FFF}};
constexpr RowSet F1c = chain_rows(R0c);
constexpr RowSet F2c = chain_rows(F1c);
constexpr RowSet G1c = chain_cols(G0c);
static_assert(G1c.r[0]==0x0400 && G1c.r[1]==0x0800 && G1c.r[2]==0x0001 && G1c.r[3]==0x0002 &&
              G1c.r[4]==0x0004 && G1c.r[5]==0x0008 && G1c.r[6]==0x0010 && G1c.r[7]==0x0020 &&
              G1c.r[8]==0x0040 && G1c.r[9]==0x0080 && G1c.r[10]==0x0100 && G1c.r[11]==0x0200 &&
              G1c.r[12]==0x1000, "single-bit gate masks after chain 1");
static_assert(F1c.r[0]==0x0400 && F1c.r[1]==0x0800 && F1c.r[2]==0x0001 && F1c.r[12]==0x1000,
              "frame after chain 1 is the bit-permutation phi");

// V = RY(c)*RZ(b)*RY(a); u = {u00,u01,u10,u11}
__device__ __forceinline__ void build_V(float wa, float wb, float wc, c2* u) {
    float a = 0.5f * wa, b = 0.5f * wb, c = 0.5f * wc;
    float sa, ca, sb, cb, sc, cc;
    __sincosf(a, &sa, &ca); __sincosf(b, &sb, &cb); __sincosf(c, &sc, &cc);
    float A = ca * cb, Bq = ca * sb, C = sa * cb, D = sa * sb;
    u[0] = make_float2( cc * A - sc * C, -cc * Bq - sc * D);
    u[1] = make_float2(-cc * C - sc * A,  cc * D - sc * Bq);
    u[2] = make_float2( sc * A + cc * C, -sc * Bq + cc * D);
    u[3] = make_float2(-sc * C + cc * A,  sc * D + cc * Bq);
}

template<int K>
__device__ __forceinline__ void gate_reg(c2* s, const float* m) {
    c2 u00 = {m[0], m[1]}, u01 = {m[2], m[3]}, u10 = {m[4], m[5]}, u11 = {m[6], m[7]};
#pragma unroll
    for (int r = 0; r < 16; ++r)
        if (!(r & (1 << K))) {
            const int r1 = r | (1 << K);
            c2 a0 = s[r], a1 = s[r1];
            s[r]  = cfma2(u00, a0, cmul2(u01, a1));
            s[r1] = cfma2(u10, a0, cmul2(u11, a1));
        }
}
template<int LM>
__device__ __forceinline__ void gate_lane(c2* s, const float* m, int lane) {
    c2 u00 = {m[0], m[1]}, u01 = {m[2], m[3]}, u10 = {m[4], m[5]}, u11 = {m[6], m[7]};
    int mb = (lane & LM) ? 1 : 0;
    c2 ua = mb ? u11 : u00, ub = mb ? u10 : u01;
#pragma unroll
    for (int r = 0; r < 16; ++r) {
        c2 pv = shflx2(s[r], LM);
        s[r] = cfma2(ua, s[r], cmul2(ub, pv));
    }
}

__global__ __launch_bounds__(BLK) void qlc_kernel(
    const float* __restrict__ h, const float* __restrict__ enc_w,
    const float* __restrict__ enc_b, const float* __restrict__ qw,
    const float* __restrict__ dec_w, const float* __restrict__ alpha,
    float* __restrict__ out, int nlayers)
{
    const int n = blockIdx.x, tid = threadIdx.x, lane = tid & 63, wv = tid >> 6;
    __shared__ c2 plane[8192];            // 64 KB; multi-purpose
    float* smem = (float*)plane;
    float* vec  = smem;                   // [13*4]  per-wire 2-vectors (by logical bit)
    float* mats = smem + 64;              // [13*8]  layer-1 gate matrices (by wire)
    c2 s[16];

    // ---------------- Phase 1: product state (encoding (+ layer-0)) --------
    for (int p = wv; p < P; p += 8) {
        float hv = h[(size_t)n * NH + p * 64 + lane];
        float a0 = hv * enc_w[lane], a1 = hv * enc_w[64 + lane], a2 = hv * enc_w[128 + lane];
#pragma unroll
        for (int m = 32; m; m >>= 1) {
            a0 += __shfl_xor(a0, m, 64); a1 += __shfl_xor(a1, m, 64); a2 += __shfl_xor(a2, m, 64);
        }
        float x = 0.5f * (a0 + enc_b[0]), y = 0.5f * (a1 + enc_b[1]), z = 0.5f * (a2 + enc_b[2]);
        float sx, cx, sy, cy, sz, cz;
        __sincosf(x, &sx, &cx); __sincosf(y, &sy, &cy); __sincosf(z, &sz, &cz);
        c2 em = {cz, -sz}, ep = {cz, sz};
        c2 u0 = cmul2(em, make_float2(cy * cx,  sy * sx));   // col0 of RZ*RY*RX
        c2 u1 = cmul2(ep, make_float2(sy * cx, -cy * sx));
        c2 w0 = u0, w1 = u1;
        if (nlayers > 0) {
            c2 u[4]; const float* q = qw + p * 3;            // layer 0
            build_V(q[0], q[1], q[2], u);
            w0 = cfma2(u[0], u0, cmul2(u[1], u1));
            w1 = cfma2(u[2], u0, cmul2(u[3], u1));
        }
        if (lane == 0) {
            int b = 12 - p;
            vec[b*4+0] = w0.x; vec[b*4+1] = w0.y; vec[b*4+2] = w1.x; vec[b*4+3] = w1.y;
        }
    }
    if (nlayers == 2 && wv == 5 && lane < P) {               // layer-1 matrices (idle slot)
        c2 u[4]; const float* q = qw + (P + lane) * 3;
        build_V(q[0], q[1], q[2], u);
        float* m = mats + lane * 8;
        m[0]=u[0].x; m[1]=u[0].y; m[2]=u[1].x; m[3]=u[1].y;
        m[4]=u[2].x; m[5]=u[2].y; m[6]=u[3].x; m[7]=u[3].y;
    }
    __syncthreads();

    // Expansion: s[p] = prod_b vec[b][parity(R0[b]&p)]
    {
        c2 pref = {1.f, 0.f};
        const int UB[8] = {0, 6, 7, 8, 9, 10, 11, 12};       // r-independent bits
#pragma unroll
        for (int k = 0; k < 8; ++k) {
            const int b = UB[k];
            int t = __popc(tid & (R0c.r[b] >> 4)) & 1;
            c2 vv = { vec[b*4 + t*2], vec[b*4 + t*2 + 1] };
            pref = cmul2(pref, vv);
        }
        int t1 = (tid >> 7) & 1, t5 = tid & 1;               // R0[1]>>4=0x80, R0[5]>>4=1
        c2 w1v[2] = { {vec[4+t1*2], vec[5+t1*2]}, {vec[4+(t1^1)*2], vec[5+(t1^1)*2]} };
        c2 w2v[2] = { {vec[8],  vec[9]},  {vec[10], vec[11]} };
        c2 w3v[2] = { {vec[12], vec[13]}, {vec[14], vec[15]} };
        c2 w4v[2] = { {vec[16], vec[17]}, {vec[18], vec[19]} };
        c2 w5v[2] = { {vec[20+t5*2], vec[21+t5*2]}, {vec[20+(t5^1)*2], vec[21+(t5^1)*2]} };
        c2 v12[4], v34[4], P5[2];
        v12[0]=cmul2(w1v[0],w2v[0]); v12[1]=cmul2(w1v[0],w2v[1]);
        v12[2]=cmul2(w1v[1],w2v[0]); v12[3]=cmul2(w1v[1],w2v[1]);
        v34[0]=cmul2(w3v[0],w4v[0]); v34[1]=cmul2(w3v[0],w4v[1]);
        v34[2]=cmul2(w3v[1],w4v[0]); v34[3]=cmul2(w3v[1],w4v[1]);
        P5[0]=cmul2(pref,w5v[0]); P5[1]=cmul2(pref,w5v[1]);
#pragma unroll
        for (int r = 0; r < 16; ++r) {
            const int i12 = ((r & 1) << 1) | ((r ^ (r >> 1)) & 1);            // bit(r&1), par(r&3)
            const int i34 = ((((r >> 1) ^ (r >> 2)) & 1) << 1) | (((r >> 2) ^ (r >> 3)) & 1);
            s[r] = cmul2(P5[(r >> 3) & 1], cmul2(v12[i12], v34[i34]));
        }
    }

    unsigned mrows[13];

    if (nlayers == 2) {
        // chain 1 is free (frame change). Layer-1 gates, all single-bit masks:
        gate_reg<0>(s, mats + 10*8);     // b=2  <- wire 10
        gate_reg<1>(s, mats +  9*8);     // b=3
        gate_reg<2>(s, mats +  8*8);     // b=4
        gate_reg<3>(s, mats +  7*8);     // b=5
        gate_lane<1 >(s, mats + 6*8, lane);   // b=6
        gate_lane<2 >(s, mats + 5*8, lane);   // b=7
        gate_lane<4 >(s, mats + 4*8, lane);   // b=8
        gate_lane<8 >(s, mats + 3*8, lane);   // b=9
        gate_lane<16>(s, mats + 2*8, lane);   // b=10
        gate_lane<32>(s, mats + 1*8, lane);   // b=11
        // LDS gates: preload matrices (mats region aliases plane)
        c2 umA[4], umB[4], umC[4];
#pragma unroll
        for (int j = 0; j < 4; ++j) {
            umA[j] = { mats[12*8 + j*2], mats[12*8 + j*2 + 1] };   // b=0  <- wire 12, tx=64
            umB[j] = { mats[11*8 + j*2], mats[11*8 + j*2 + 1] };   // b=1  <- wire 11, tx=128
            umC[j] = { mats[ 0*8 + j*2], mats[ 0*8 + j*2 + 1] };   // b=12 <- wire 0,  tx=256
        }
        __syncthreads();                 // all vec/mats reads done before staging
        {
            const c2* um[3] = {umA, umB, umC};
            const int  tx[3] = {64, 128, 256};
#pragma unroll
            for (int g = 0; g < 3; ++g) {
#pragma unroll
                for (int r = 0; r < 16; ++r) plane[r*512 + tid] = s[r];
                __syncthreads();
                int pt = tid ^ tx[g];
                int mb = (tid & tx[g]) ? 1 : 0;
                c2 ua = mb ? um[g][3] : um[g][0];
                c2 ub = mb ? um[g][2] : um[g][1];
#pragma unroll
                for (int r = 0; r < 16; ++r) {
                    c2 pv = plane[r*512 + pt];
                    s[r] = cfma2(ua, s[r], cmul2(ub, pv));
                }
                __syncthreads();
            }
        }
        // chain 2 free; measurement rows are compile-time:
#pragma unroll
        for (int b = 0; b < 13; ++b) mrows[b] = F2c.r[b];
    } else {
        // -------- generic fallback (any nlayers != 2): staged gates --------
        unsigned rowF[13], colG[13];
#pragma unroll
        for (int b = 0; b < 13; ++b) { rowF[b] = R0c.r[b]; colG[b] = G0c.r[b]; }
        for (int l = 1; l < nlayers; ++l) {
#pragma unroll
            for (int i = 0; i < P; ++i) { int bc = 12-i, bt = (i==12)?12:(11-i); rowF[bt]^=rowF[bc]; colG[bc]^=colG[bt]; }
#pragma unroll
            for (int b = 0; b < 13; ++b) {
                const float* q = qw + ((size_t)l * P + (12 - b)) * 3;
                c2 u[4]; build_V(q[0], q[1], q[2], u);       // uniform, redundant per thread
                __syncthreads();
#pragma unroll
                for (int r = 0; r < 16; ++r) plane[r*512 + tid] = s[r];
                __syncthreads();
                unsigned m = colG[b], row = rowF[b];
                int pt = tid ^ (int)(m >> 4);
                unsigned mr = m & 15, rl = row & 15;
                int bt_ = __popc(tid & (row >> 4)) & 1;
#pragma unroll
                for (int r = 0; r < 16; ++r) {
                    c2 pv = plane[((r ^ mr) & 15) * 512 + pt];
                    int beta = bt_ ^ (__popc(r & rl) & 1);
                    c2 ua = beta ? u[3] : u[0], ub = beta ? u[2] : u[1];
                    s[r] = cfma2(ua, s[r], cmul2(ub, pv));
                }
            }
        }
        if (nlayers >= 1) {
#pragma unroll
            for (int i = 0; i < P; ++i) { int bc = 12-i, bt = (i==12)?12:(11-i); rowF[bt]^=rowF[bc]; colG[bc]^=colG[bt]; }
        }
#pragma unroll
        for (int b = 0; b < 13; ++b) mrows[b] = rowF[b];
    }

    // ---------------- Measure <Z_w> + decode --------------------------------
    float pr[16];
#pragma unroll
    for (int r = 0; r < 16; ++r) pr[r] = fmaf(s[r].x, s[r].x, s[r].y * s[r].y);
    float ev[13];
#pragma unroll
    for (int b = 0; b < 13; ++b) {
        unsigned row = mrows[b];
        int tp = __popc(tid & (row >> 4)) & 1;
        float acc = 0.f;
#pragma unroll
        for (int r = 0; r < 16; ++r)
            acc += (__popc((unsigned)r & row) & 1) ? -pr[r] : pr[r];
        ev[12 - b] = tp ? -acc : acc;    // wire w = 12-b
    }
#pragma unroll
    for (int w = 0; w < 13; ++w) {
#pragma unroll
        for (int m = 32; m; m >>= 1) ev[w] += __shfl_xor(ev[w], m, 64);
    }
    float* red  = smem + 256;
    float* red2 = smem + 384;
    __syncthreads();                     // all plane reads done; reuse LDS
    if (lane == 0) {
#pragma unroll
        for (int w = 0; w < 13; ++w) red[wv * 13 + w] = ev[w];
    }
    __syncthreads();
    if (tid < 13) {
        float sum = 0.f;
        for (int q = 0; q < 8; ++q) sum += red[q * 13 + tid];
        red2[tid] = sum;
    }
    __syncthreads();
    float al = alpha[0];
    for (int idx = tid; idx < NH; idx += BLK) {
        size_t off = (size_t)n * NH + idx;
        out[off] = fmaf(al * red2[idx >> 6], dec_w[idx & 63], h[off]);
    }
}

extern "C" void kernel_launch(void* const* d_in, const int* in_sizes, int n_in,
                              void* d_out, int out_size, void* d_ws, size_t ws_size,
                              hipStream_t stream) {
    const float* h     = (const float*)d_in[0];
    const float* enc_w = (const float*)d_in[1];
    const float* enc_b = (const float*)d_in[2];
    const float* qw    = (const float*)d_in[3];
    const float* dec_w = (const float*)d_in[4];
    const float* alpha = (const float*)d_in[5];
    float* out = (float*)d_out;

    int N = in_sizes[0] / NH;          // B*T samples
    int L = in_sizes[3] / (P * 3);     // variational layers

    qlc_kernel<<<N, BLK, 0, stream>>>(h, enc_w, enc_b, qw, dec_w, alpha, out, L);
}